// Round 1
// baseline (340.136 us; speedup 1.0000x reference)
//
#include <hip/hip_runtime.h>

#define HH 200
#define WW 196
#define CC 256
#define NCAMS 6
#define NPTS (HH * WW)          // 39200
#define SSZ 400
#define NCELLS (SSZ * SSZ)      // 160000

// Main fused kernel: per (cam, point) compute dot(feats, w_cls), transform
// point into the BEV grid, and atomically scatter scalar + count.
__global__ __launch_bounds__(256)
void pon_scatter_kernel(const float* __restrict__ feats,      // (6, 256, 196, 200)
                        const float* __restrict__ cam2ego,    // (6, 4, 4)
                        const float* __restrict__ lcoords,    // (4, 39200)
                        const unsigned char* __restrict__ mask_raw, // bool (200,196), width unknown
                        const float* __restrict__ w_cls,      // (256,)
                        float* __restrict__ sums,             // (160000,)
                        float* __restrict__ cnt)              // (160000,)
{
    __shared__ float w_s[CC];
    __shared__ int mask_is_wide;   // 1 => 4 bytes/elem, 0 => 1 byte/elem

    const int tid = threadIdx.x;
    if (tid < CC) w_s[tid] = w_cls[tid];   // blockDim.x == 256 == CC

    if (tid == 0) {
        // Detect mask element width. In a 1-byte (bool/uint8) layout with ~90%
        // true, 32-bit words pack 4 bytes like 0x01010101 — essentially never
        // in {0, 1, 0x3f800000}. In int32/float32 layouts every word IS in
        // that set. Sample 64 words (256 B, safe under either layout size).
        const unsigned int* mw = (const unsigned int*)mask_raw;
        int wide = 1;
        for (int k = 0; k < 64; ++k) {
            unsigned int v = mw[k];
            if (!(v == 0u || v == 1u || v == 0x3f800000u)) wide = 0;
        }
        mask_is_wide = wide;
    }
    __syncthreads();

    const int cam = blockIdx.y;
    const int i = blockIdx.x * blockDim.x + tid;   // plane index: i = w*200 + h
    if (i >= NPTS) return;

    // ---- 256-channel dot product, coalesced (stride NPTS between channels) ----
    const float* fbase = feats + (size_t)cam * CC * NPTS + i;
    float acc = 0.0f;
    #pragma unroll 16
    for (int ch = 0; ch < CC; ++ch) {
        acc = fmaf(w_s[ch], fbase[(size_t)ch * NPTS], acc);
    }

    // ---- coordinate transform (must be bit-exact vs numpy reference) ----
    const int h = i % HH;
    const int w = i / HH;
    const int n = h * WW + w;           // reference's flat point index

    const float x = lcoords[n];          // row 0: x
    const float y = lcoords[NPTS + n];   // row 1: y
    // rows 2 (z=0) and 3 (ones) contribute exactly 0 / m03 — no-ops in fp32.

    const float* M = cam2ego + cam * 16;
    // Strict IEEE mul/add, j-ascending, no fma contraction — mirrors
    // np.einsum's sequential accumulation:  ((m00*x + m01*y) + m02*0) + m03*1
    float ex = __fadd_rn(__fadd_rn(__fmul_rn(M[0], x), __fmul_rn(M[1], y)), M[3]);
    float ey = __fadd_rn(__fadd_rn(__fmul_rn(M[4], x), __fmul_rn(M[5], y)), M[7]);

    // (c + 100) / 0.5  ==  (c + 100) * 2  (exact); jnp.round == half-even == rintf
    int i0 = (int)rintf(__fmul_rn(__fadd_rn(ex, 100.0f), 2.0f));
    int i1 = (int)rintf(__fmul_rn(__fadd_rn(ey, 100.0f), 2.0f));

    bool m;
    if (mask_is_wide) m = (((const unsigned int*)mask_raw)[n] != 0u);
    else              m = (mask_raw[n] != 0);

    const bool valid = m & (i0 >= 0) & (i0 < SSZ) & (i1 >= 0) & (i1 < SSZ);
    if (valid) {
        const int cell = i0 * SSZ + i1;
        atomicAdd(&sums[cell], acc);
        atomicAdd(&cnt[cell], 1.0f);
    }
}

__global__ __launch_bounds__(256)
void pon_finalize_kernel(const float* __restrict__ sums,
                         const float* __restrict__ cnt,
                         const float* __restrict__ b_cls,
                         float* __restrict__ out)
{
    const int c = blockIdx.x * blockDim.x + threadIdx.x;
    if (c < NCELLS) {
        const float cc = cnt[c];
        // cnt==0 cells have sums==0 exactly (only valid points scatter),
        // so out = 0 + b there — matches reference's where().
        const float v = (cc >= 1.0f) ? (sums[c] / cc) : 0.0f;
        out[c] = v + b_cls[0];
    }
}

extern "C" void kernel_launch(void* const* d_in, const int* in_sizes, int n_in,
                              void* d_out, int out_size, void* d_ws, size_t ws_size,
                              hipStream_t stream) {
    const float* td_feats  = (const float*)d_in[0];
    const float* cam2ego   = (const float*)d_in[1];
    const float* lcoords   = (const float*)d_in[2];
    const unsigned char* mask = (const unsigned char*)d_in[3];
    const float* w_cls     = (const float*)d_in[4];
    const float* b_cls     = (const float*)d_in[5];
    float* out = (float*)d_out;

    float* sums = (float*)d_ws;
    float* cnt  = sums + NCELLS;

    // d_ws is re-poisoned to 0xAA before every launch — zero the accumulators.
    hipMemsetAsync(d_ws, 0, (size_t)2 * NCELLS * sizeof(float), stream);

    dim3 block(256);
    dim3 grid((NPTS + 255) / 256, NCAMS);
    pon_scatter_kernel<<<grid, block, 0, stream>>>(
        td_feats, cam2ego, lcoords, mask, w_cls, sums, cnt);

    pon_finalize_kernel<<<(NCELLS + 255) / 256, 256, 0, stream>>>(
        sums, cnt, b_cls, out);
}